// Round 1
// baseline (37724.814 us; speedup 1.0000x reference)
//
#include <hip/hip_runtime.h>
#include <math.h>

namespace {

constexpr int Bq = 64, Pq = 196, Dq = 2048, Eq = 512, Vq = 10000, Tq = 32, T1q = 33;

enum Act { ACT_NONE = 0, ACT_TANH = 1, ACT_SIG = 2 };

__device__ __forceinline__ float sigf(float x) { return 1.f / (1.f + expf(-x)); }

// C = act(A @ W^T + bias). A:(M,K), W:(N,K), C:(M,N), all row-major fp32.
// Requires M%64==0, N%64==0, K%32==0. grid = (M/64, N/64), block = 256.
template <int ACT>
__global__ __launch_bounds__(256) void gemm_tn(const float* __restrict__ A,
                                               const float* __restrict__ W,
                                               const float* __restrict__ bias,
                                               float* __restrict__ C,
                                               int M, int N, int K) {
  __shared__ float As[32][66];
  __shared__ float Ws[32][66];
  const int tid = threadIdx.x;
  const int tx = tid & 15, ty = tid >> 4;
  const int m0 = blockIdx.x * 64, n0 = blockIdx.y * 64;
  float acc[4][4] = {};
  for (int k0 = 0; k0 < K; k0 += 32) {
#pragma unroll
    for (int i = 0; i < 2; ++i) {
      int idx = tid + i * 256;
      int r = idx >> 3, c = (idx & 7) << 2;
      const float4 a = *reinterpret_cast<const float4*>(A + (size_t)(m0 + r) * K + k0 + c);
      As[c + 0][r] = a.x; As[c + 1][r] = a.y; As[c + 2][r] = a.z; As[c + 3][r] = a.w;
      const float4 w = *reinterpret_cast<const float4*>(W + (size_t)(n0 + r) * K + k0 + c);
      Ws[c + 0][r] = w.x; Ws[c + 1][r] = w.y; Ws[c + 2][r] = w.z; Ws[c + 3][r] = w.w;
    }
    __syncthreads();
#pragma unroll
    for (int k = 0; k < 32; ++k) {
      float a[4], w[4];
#pragma unroll
      for (int i = 0; i < 4; ++i) { a[i] = As[k][ty * 4 + i]; w[i] = Ws[k][tx * 4 + i]; }
#pragma unroll
      for (int mi = 0; mi < 4; ++mi)
#pragma unroll
        for (int ni = 0; ni < 4; ++ni) acc[mi][ni] = fmaf(a[mi], w[ni], acc[mi][ni]);
    }
    __syncthreads();
  }
#pragma unroll
  for (int ni = 0; ni < 4; ++ni) {
    int n = n0 + tx * 4 + ni;
    float bv = bias ? bias[n] : 0.f;
#pragma unroll
    for (int mi = 0; mi < 4; ++mi) {
      float v = acc[mi][ni] + bv;
      if (ACT == ACT_TANH) v = tanhf(v);
      else if (ACT == ACT_SIG) v = sigf(v);
      C[(size_t)(m0 + ty * 4 + mi) * N + n] = v;
    }
  }
}

// preds GEMM: h2(64,512) @ W_out(10000,512)^T + b_out -> out[b*T*V + t*V + n]
// grid = 157 (N tiles), block = 256. C = d_out + t*V, row stride T*V.
__global__ __launch_bounds__(256) void gemm_out(const float* __restrict__ A,
                                                const float* __restrict__ W,
                                                const float* __restrict__ bias,
                                                float* __restrict__ C) {
  __shared__ float As[32][66];
  __shared__ float Ws[32][66];
  const int tid = threadIdx.x;
  const int tx = tid & 15, ty = tid >> 4;
  const int n0 = blockIdx.x * 64;
  float acc[4][4] = {};
  for (int k0 = 0; k0 < Eq; k0 += 32) {
#pragma unroll
    for (int i = 0; i < 2; ++i) {
      int idx = tid + i * 256;
      int r = idx >> 3, c = (idx & 7) << 2;
      const float4 a = *reinterpret_cast<const float4*>(A + (size_t)r * Eq + k0 + c);
      As[c + 0][r] = a.x; As[c + 1][r] = a.y; As[c + 2][r] = a.z; As[c + 3][r] = a.w;
      int wr = n0 + r; if (wr > Vq - 1) wr = Vq - 1;
      const float4 w = *reinterpret_cast<const float4*>(W + (size_t)wr * Eq + k0 + c);
      Ws[c + 0][r] = w.x; Ws[c + 1][r] = w.y; Ws[c + 2][r] = w.z; Ws[c + 3][r] = w.w;
    }
    __syncthreads();
#pragma unroll
    for (int k = 0; k < 32; ++k) {
      float a[4], w[4];
#pragma unroll
      for (int i = 0; i < 4; ++i) { a[i] = As[k][ty * 4 + i]; w[i] = Ws[k][tx * 4 + i]; }
#pragma unroll
      for (int mi = 0; mi < 4; ++mi)
#pragma unroll
        for (int ni = 0; ni < 4; ++ni) acc[mi][ni] = fmaf(a[mi], w[ni], acc[mi][ni]);
    }
    __syncthreads();
  }
#pragma unroll
  for (int ni = 0; ni < 4; ++ni) {
    int n = n0 + tx * 4 + ni;
    if (n < Vq) {
      float bv = bias[n];
#pragma unroll
      for (int mi = 0; mi < 4; ++mi) {
        C[(size_t)(ty * 4 + mi) * ((size_t)Tq * Vq) + n] = acc[mi][ni] + bv;
      }
    }
  }
}

// avg[b,d] = mean_p img[b,p,d]; grid = B*D/256
__global__ __launch_bounds__(256) void avg_kernel(const float* __restrict__ img,
                                                  float* __restrict__ avg) {
  int idx = blockIdx.x * 256 + threadIdx.x;
  int b = idx >> 11, d = idx & (Dq - 1);
  const float* ib = img + (size_t)b * Pq * Dq + d;
  float s = 0.f;
  for (int p = 0; p < Pq; ++p) s += ib[(size_t)p * Dq];
  avg[idx] = s * (1.f / Pq);
}

// Per-b fused attention: att_h = h@U^T + b, e_p = tanh(fproj+att_h)@v + bv, softmax.
// grid = B, block = 256 (4 waves).
__global__ __launch_bounds__(256) void attention_kernel(
    const float* __restrict__ h, const float* __restrict__ U_att,
    const float* __restrict__ b_Uatt, const float* __restrict__ fproj,
    const float* __restrict__ v_att, const float* __restrict__ b_vatt,
    float* __restrict__ alpha, float* __restrict__ alphas_out, int t) {
  const int b = blockIdx.x;
  const int tid = threadIdx.x;
  const int lane = tid & 63, w = tid >> 6;
  __shared__ float hs[Eq];
  __shared__ float vs[Eq];
  __shared__ float ah[Eq];
  __shared__ float ev[Pq];
  __shared__ float red[256];
  for (int i = tid; i < Eq; i += 256) { hs[i] = h[b * Eq + i]; vs[i] = v_att[i]; }
  __syncthreads();
  // att_h: one wave per output element group
  for (int e = w; e < Eq; e += 4) {
    const float* Ur = U_att + (size_t)e * Eq;
    float s = 0.f;
#pragma unroll
    for (int j = 0; j < 8; ++j) { int k = j * 64 + lane; s = fmaf(Ur[k], hs[k], s); }
#pragma unroll
    for (int off = 32; off > 0; off >>= 1) s += __shfl_xor(s, off);
    if (lane == 0) ah[e] = s + b_Uatt[e];
  }
  __syncthreads();
  // e_p
  const float bv = b_vatt[0];
  for (int p = w; p < Pq; p += 4) {
    const float* fp = fproj + ((size_t)b * Pq + p) * Eq;
    float s = 0.f;
#pragma unroll
    for (int j = 0; j < 8; ++j) {
      int k = j * 64 + lane;
      s = fmaf(tanhf(fp[k] + ah[k]), vs[k], s);
    }
#pragma unroll
    for (int off = 32; off > 0; off >>= 1) s += __shfl_xor(s, off);
    if (lane == 0) ev[p] = s + bv;
  }
  __syncthreads();
  // softmax over ev[0..195]
  float x = (tid < Pq) ? ev[tid] : -INFINITY;
  red[tid] = x;
  __syncthreads();
  for (int s = 128; s > 0; s >>= 1) {
    if (tid < s) red[tid] = fmaxf(red[tid], red[tid + s]);
    __syncthreads();
  }
  float mx = red[0];
  __syncthreads();
  float ex = (tid < Pq) ? expf(x - mx) : 0.f;
  red[tid] = ex;
  __syncthreads();
  for (int s = 128; s > 0; s >>= 1) {
    if (tid < s) red[tid] += red[tid + s];
    __syncthreads();
  }
  float inv = 1.f / red[0];
  if (tid < Pq) {
    float a = ex * inv;
    alpha[b * Pq + tid] = a;
    alphas_out[((size_t)b * Tq + t) * Pq + tid] = a;
  }
}

// ctxg[b,d] = gate[b,d] * sum_p alpha[b,p]*img[b,p,d]; grid = (D/256, B)
__global__ __launch_bounds__(256) void context_kernel(const float* __restrict__ alpha,
                                                      const float* __restrict__ img,
                                                      const float* __restrict__ gate,
                                                      float* __restrict__ ctxg) {
  const int b = blockIdx.y;
  const int d = blockIdx.x * 256 + threadIdx.x;
  __shared__ float al[Pq];
  if (threadIdx.x < Pq) al[threadIdx.x] = alpha[b * Pq + threadIdx.x];
  __syncthreads();
  const float* ib = img + (size_t)b * Pq * Dq + d;
  float s = 0.f;
#pragma unroll 4
  for (int p = 0; p < Pq; ++p) s = fmaf(al[p], ib[(size_t)p * Dq], s);
  ctxg[b * Dq + d] = s * gate[b * Dq + d];
}

// gates = [emb_t | ctxg | h] @ [W_ih | W_hh]^T + b_ih + b_hh, fused LSTM update.
// grid = E/64 blocks; block computes 64b x 64e for all 4 gates (K = 3072 virtual).
__global__ __launch_bounds__(256) void gates_lstm_kernel(
    const float* __restrict__ emb, const int* __restrict__ captions,
    const float* __restrict__ ctxg, const float* __restrict__ h,
    const float* __restrict__ c, const float* __restrict__ W_ih,
    const float* __restrict__ b_ih, const float* __restrict__ W_hh,
    const float* __restrict__ b_hh, float* __restrict__ h2,
    float* __restrict__ c2, int t) {
  __shared__ float As[32][66];
  __shared__ float Ws[32][258];
  const int tid = threadIdx.x;
  const int tx = tid & 15, ty = tid >> 4;
  const int e0 = blockIdx.x * 64;
  float acc[4][4][4] = {};  // [gate][mi][ni]
  for (int k0 = 0; k0 < 3072; k0 += 32) {
    // A tile: 64 b-rows x 32 k
#pragma unroll
    for (int i = 0; i < 2; ++i) {
      int id2 = tid + i * 256;
      int r = id2 >> 3, cc = (id2 & 7) << 2;
      int k = k0 + cc;
      float4 a;
      if (k0 < 512) {
        int tok = captions[r * T1q + t];
        a = *reinterpret_cast<const float4*>(emb + (size_t)tok * Eq + k);
      } else if (k0 < 2560) {
        a = *reinterpret_cast<const float4*>(ctxg + (size_t)r * Dq + (k - 512));
      } else {
        a = *reinterpret_cast<const float4*>(h + (size_t)r * Eq + (k - 2560));
      }
      As[cc + 0][r] = a.x; As[cc + 1][r] = a.y; As[cc + 2][r] = a.z; As[cc + 3][r] = a.w;
    }
    // W tile: 256 rows (4 gates x 64 e) x 32 k
#pragma unroll
    for (int i = 0; i < 8; ++i) {
      int id2 = tid + i * 256;
      int r = id2 >> 3, cc = (id2 & 7) << 2;
      int g = r >> 6, el = r & 63;
      int row = g * Eq + e0 + el;
      int k = k0 + cc;
      float4 wv;
      if (k0 < 2560) wv = *reinterpret_cast<const float4*>(W_ih + (size_t)row * 2560 + k);
      else wv = *reinterpret_cast<const float4*>(W_hh + (size_t)row * Eq + (k - 2560));
      Ws[cc + 0][r] = wv.x; Ws[cc + 1][r] = wv.y; Ws[cc + 2][r] = wv.z; Ws[cc + 3][r] = wv.w;
    }
    __syncthreads();
#pragma unroll
    for (int k = 0; k < 32; ++k) {
      float a[4];
#pragma unroll
      for (int mi = 0; mi < 4; ++mi) a[mi] = As[k][ty * 4 + mi];
#pragma unroll
      for (int g = 0; g < 4; ++g) {
        float wv[4];
#pragma unroll
        for (int ni = 0; ni < 4; ++ni) wv[ni] = Ws[k][g * 64 + tx * 4 + ni];
#pragma unroll
        for (int mi = 0; mi < 4; ++mi)
#pragma unroll
          for (int ni = 0; ni < 4; ++ni)
            acc[g][mi][ni] = fmaf(a[mi], wv[ni], acc[g][mi][ni]);
      }
    }
    __syncthreads();
  }
#pragma unroll
  for (int ni = 0; ni < 4; ++ni) {
    int e = e0 + tx * 4 + ni;
    float b0 = b_ih[e] + b_hh[e];
    float b1 = b_ih[Eq + e] + b_hh[Eq + e];
    float b2 = b_ih[2 * Eq + e] + b_hh[2 * Eq + e];
    float b3 = b_ih[3 * Eq + e] + b_hh[3 * Eq + e];
#pragma unroll
    for (int mi = 0; mi < 4; ++mi) {
      int bb = ty * 4 + mi;
      float ig = sigf(acc[0][mi][ni] + b0);
      float fg = sigf(acc[1][mi][ni] + b1);
      float gg = tanhf(acc[2][mi][ni] + b2);
      float og = sigf(acc[3][mi][ni] + b3);
      float cp = c[bb * Eq + e];
      float cn_ = fg * cp + ig * gg;
      float hn_ = og * tanhf(cn_);
      c2[bb * Eq + e] = cn_;
      h2[bb * Eq + e] = hn_;
    }
  }
}

}  // namespace

extern "C" void kernel_launch(void* const* d_in, const int* in_sizes, int n_in,
                              void* d_out, int out_size, void* d_ws, size_t ws_size,
                              hipStream_t stream) {
  (void)in_sizes; (void)n_in; (void)out_size; (void)ws_size;
  const float* img      = (const float*)d_in[0];
  const int*   caps     = (const int*)d_in[1];
  const float* emb      = (const float*)d_in[2];
  const float* W_init_h = (const float*)d_in[3];
  const float* b_init_h = (const float*)d_in[4];
  const float* W_init_c = (const float*)d_in[5];
  const float* b_init_c = (const float*)d_in[6];
  const float* W_fbeta  = (const float*)d_in[7];
  const float* b_fbeta  = (const float*)d_in[8];
  const float* U_att    = (const float*)d_in[9];
  const float* b_Uatt   = (const float*)d_in[10];
  const float* W_att    = (const float*)d_in[11];
  const float* b_Watt   = (const float*)d_in[12];
  const float* v_att    = (const float*)d_in[13];
  const float* b_vatt   = (const float*)d_in[14];
  const float* W_ih     = (const float*)d_in[15];
  const float* b_ih     = (const float*)d_in[16];
  const float* W_hh     = (const float*)d_in[17];
  const float* b_hh     = (const float*)d_in[18];
  const float* W_out    = (const float*)d_in[19];
  const float* b_out    = (const float*)d_in[20];

  float* out = (float*)d_out;
  float* alphas_out = out + (size_t)Bq * Tq * Vq;

  float* ws = (float*)d_ws;
  float* avg   = ws; ws += (size_t)Bq * Dq;
  float* fproj = ws; ws += (size_t)Bq * Pq * Eq;
  float* h0 = ws; ws += Bq * Eq;
  float* h1 = ws; ws += Bq * Eq;
  float* c0 = ws; ws += Bq * Eq;
  float* c1 = ws; ws += Bq * Eq;
  float* alpha = ws; ws += Bq * Pq;
  float* gatebuf = ws; ws += Bq * Dq;
  float* ctxg = ws; ws += Bq * Dq;

  // Precompute
  avg_kernel<<<Bq * Dq / 256, 256, 0, stream>>>(img, avg);
  gemm_tn<ACT_TANH><<<dim3(1, Eq / 64), 256, 0, stream>>>(avg, W_init_h, b_init_h, h0, Bq, Eq, Dq);
  gemm_tn<ACT_TANH><<<dim3(1, Eq / 64), 256, 0, stream>>>(avg, W_init_c, b_init_c, c0, Bq, Eq, Dq);
  gemm_tn<ACT_NONE><<<dim3(Bq * Pq / 64, Eq / 64), 256, 0, stream>>>(img, W_att, b_Watt, fproj,
                                                                     Bq * Pq, Eq, Dq);

  float* hc = h0; float* cc_ = c0; float* hn = h1; float* cn = c1;
  for (int t = 0; t < Tq; ++t) {
    attention_kernel<<<Bq, 256, 0, stream>>>(hc, U_att, b_Uatt, fproj, v_att, b_vatt, alpha,
                                             alphas_out, t);
    gemm_tn<ACT_SIG><<<dim3(1, Dq / 64), 256, 0, stream>>>(hc, W_fbeta, b_fbeta, gatebuf, Bq, Dq, Eq);
    context_kernel<<<dim3(Dq / 256, Bq), 256, 0, stream>>>(alpha, img, gatebuf, ctxg);
    gates_lstm_kernel<<<Eq / 64, 256, 0, stream>>>(emb, caps, ctxg, hc, cc_, W_ih, b_ih, W_hh,
                                                   b_hh, hn, cn, t);
    gemm_out<<<157, 256, 0, stream>>>(hn, W_out, b_out, out + (size_t)t * Vq);
    float* tmp = hc; hc = hn; hn = tmp;
    tmp = cc_; cc_ = cn; cn = tmp;
  }
}

// Round 2
// 11199.132 us; speedup vs baseline: 3.3685x; 3.3685x over previous
//
#include <hip/hip_runtime.h>
#include <math.h>

namespace {

constexpr int Bq = 64, Pq = 196, Dq = 2048, Eq = 512, Vq = 10000, Tq = 32, T1q = 33;
constexpr int VqPad = 10048;  // 157*64

enum Act { ACT_NONE = 0, ACT_TANH = 1, ACT_SIG = 2 };

__device__ __forceinline__ float sigf(float x) { return 1.f / (1.f + expf(-x)); }

// C = act(A @ W^T + bias). A:(M,K), W:(N,K), C:(M,N), all row-major fp32.
// Requires M%64==0, N%64==0, K%32==0. grid = (M/64, N/64), block = 256.
// Used only for the big one-time feat_proj GEMM (M=12544 -> 1568 blocks).
template <int ACT>
__global__ __launch_bounds__(256) void gemm_tn(const float* __restrict__ A,
                                               const float* __restrict__ W,
                                               const float* __restrict__ bias,
                                               float* __restrict__ C,
                                               int M, int N, int K) {
  __shared__ float As[32][66];
  __shared__ float Ws[32][66];
  const int tid = threadIdx.x;
  const int tx = tid & 15, ty = tid >> 4;
  const int m0 = blockIdx.x * 64, n0 = blockIdx.y * 64;
  float acc[4][4] = {};
  for (int k0 = 0; k0 < K; k0 += 32) {
#pragma unroll
    for (int i = 0; i < 2; ++i) {
      int idx = tid + i * 256;
      int r = idx >> 3, c = (idx & 7) << 2;
      const float4 a = *reinterpret_cast<const float4*>(A + (size_t)(m0 + r) * K + k0 + c);
      As[c + 0][r] = a.x; As[c + 1][r] = a.y; As[c + 2][r] = a.z; As[c + 3][r] = a.w;
      const float4 w = *reinterpret_cast<const float4*>(W + (size_t)(n0 + r) * K + k0 + c);
      Ws[c + 0][r] = w.x; Ws[c + 1][r] = w.y; Ws[c + 2][r] = w.z; Ws[c + 3][r] = w.w;
    }
    __syncthreads();
#pragma unroll
    for (int k = 0; k < 32; ++k) {
      float a[4], w[4];
#pragma unroll
      for (int i = 0; i < 4; ++i) { a[i] = As[k][ty * 4 + i]; w[i] = Ws[k][tx * 4 + i]; }
#pragma unroll
      for (int mi = 0; mi < 4; ++mi)
#pragma unroll
        for (int ni = 0; ni < 4; ++ni) acc[mi][ni] = fmaf(a[mi], w[ni], acc[mi][ni]);
    }
    __syncthreads();
  }
#pragma unroll
  for (int ni = 0; ni < 4; ++ni) {
    int n = n0 + tx * 4 + ni;
    float bv = bias ? bias[n] : 0.f;
#pragma unroll
    for (int mi = 0; mi < 4; ++mi) {
      float v = acc[mi][ni] + bv;
      if (ACT == ACT_TANH) v = tanhf(v);
      else if (ACT == ACT_SIG) v = sigf(v);
      C[(size_t)(m0 + ty * 4 + mi) * N + n] = v;
    }
  }
}

// Split-K partial GEMM for the small-M (M=64) per-step GEMMs.
// P[split][64][Npad] += A(64,K) @ W(N,K)^T over this split's K-range.
// MODE 0: plain A (lda = ldW). MODE 1: A = [emb_t | ctxg | h] gather, W = [W_ih | W_hh].
// grid = (ceil(N/64), n_splits), block = 256.
template <int MODE>
__global__ __launch_bounds__(256) void gemm_partial(
    const float* __restrict__ A, const float* __restrict__ W,
    float* __restrict__ P, int N, int ldW, int iters, int Npad,
    const float* __restrict__ emb, const int* __restrict__ caps,
    const float* __restrict__ ctxg, const float* __restrict__ h,
    const float* __restrict__ W2, int t) {
  __shared__ float As[32][66];
  __shared__ float Ws[32][66];
  const int tid = threadIdx.x;
  const int tx = tid & 15, ty = tid >> 4;
  const int n0 = blockIdx.x * 64;
  const int split = blockIdx.y;
  const int kbeg = split * iters * 32;
  float acc[4][4] = {};
  for (int it = 0; it < iters; ++it) {
    const int k0 = kbeg + it * 32;
    // A tile: 64 rows x 32 k (512 float4 over 2 rounds)
#pragma unroll
    for (int i = 0; i < 2; ++i) {
      int idx = tid + i * 256;
      int r = idx >> 3, c = (idx & 7) << 2;
      float4 a;
      if (MODE == 0) {
        a = *reinterpret_cast<const float4*>(A + (size_t)r * ldW + k0 + c);
      } else {
        int k = k0 + c;
        if (k0 < Eq) {
          int tok = caps[r * T1q + t];
          a = *reinterpret_cast<const float4*>(emb + (size_t)tok * Eq + k);
        } else if (k0 < Eq + Dq) {
          a = *reinterpret_cast<const float4*>(ctxg + (size_t)r * Dq + (k - Eq));
        } else {
          a = *reinterpret_cast<const float4*>(h + (size_t)r * Eq + (k - Eq - Dq));
        }
      }
      As[c + 0][r] = a.x; As[c + 1][r] = a.y; As[c + 2][r] = a.z; As[c + 3][r] = a.w;
      // W tile
      int wr = n0 + r; if (wr >= N) wr = N - 1;
      float4 w;
      if (MODE == 0) {
        w = *reinterpret_cast<const float4*>(W + (size_t)wr * ldW + k0 + c);
      } else {
        int k = k0 + c;
        if (k0 < Eq + Dq) w = *reinterpret_cast<const float4*>(W + (size_t)wr * (Eq + Dq) + k);
        else w = *reinterpret_cast<const float4*>(W2 + (size_t)wr * Eq + (k - Eq - Dq));
      }
      Ws[c + 0][r] = w.x; Ws[c + 1][r] = w.y; Ws[c + 2][r] = w.z; Ws[c + 3][r] = w.w;
    }
    __syncthreads();
#pragma unroll
    for (int k = 0; k < 32; ++k) {
      float a[4], w[4];
#pragma unroll
      for (int i = 0; i < 4; ++i) { a[i] = As[k][ty * 4 + i]; w[i] = Ws[k][tx * 4 + i]; }
#pragma unroll
      for (int mi = 0; mi < 4; ++mi)
#pragma unroll
        for (int ni = 0; ni < 4; ++ni) acc[mi][ni] = fmaf(a[mi], w[ni], acc[mi][ni]);
    }
    __syncthreads();
  }
  float* Pb = P + (size_t)split * 64 * Npad;
#pragma unroll
  for (int ni = 0; ni < 4; ++ni) {
    int n = n0 + tx * 4 + ni;
#pragma unroll
    for (int mi = 0; mi < 4; ++mi) Pb[(size_t)(ty * 4 + mi) * Npad + n] = acc[mi][ni];
  }
}

// C[b*ld + n] = act(sum_s P[s][b][N] + bias[n]); total = 64*N elems, one per thread.
template <int ACT>
__global__ __launch_bounds__(256) void reduce_act_epilogue(const float* __restrict__ P,
                                                           const float* __restrict__ bias,
                                                           float* __restrict__ C, int N,
                                                           int S) {
  int idx = blockIdx.x * 256 + threadIdx.x;
  int b = idx / N, n = idx - b * N;
  float s = bias[n];
  for (int i = 0; i < S; ++i) s += P[((size_t)i * 64 + b) * N + n];
  if (ACT == ACT_TANH) s = tanhf(s);
  else if (ACT == ACT_SIG) s = sigf(s);
  C[(size_t)b * N + n] = s;
}

// out[b, t, n] = sum_s P[s][b][n] + b_out[n]. grid = (40, 64).
__global__ __launch_bounds__(256) void out_epilogue(const float* __restrict__ P,
                                                    const float* __restrict__ bias,
                                                    float* __restrict__ out, int t) {
  int n = blockIdx.x * 256 + threadIdx.x;
  int b = blockIdx.y;
  if (n >= Vq) return;
  float s = bias[n];
#pragma unroll
  for (int i = 0; i < 2; ++i) s += P[((size_t)i * 64 + b) * VqPad + n];
  out[((size_t)b * Tq + t) * Vq + n] = s;
}

// avg[b,d] = mean_p img[b,p,d]; grid = B*D/256
__global__ __launch_bounds__(256) void avg_kernel(const float* __restrict__ img,
                                                  float* __restrict__ avg) {
  int idx = blockIdx.x * 256 + threadIdx.x;
  int b = idx >> 11, d = idx & (Dq - 1);
  const float* ib = img + (size_t)b * Pq * Dq + d;
  float s = 0.f;
  for (int p = 0; p < Pq; ++p) s += ib[(size_t)p * Dq];
  avg[idx] = s * (1.f / Pq);
}

// Per-b fused attention: att_h = h@U^T + b, e_p = tanh(fproj+att_h)@v + bv, softmax.
// grid = B, block = 256 (4 waves).
__global__ __launch_bounds__(256) void attention_kernel(
    const float* __restrict__ h, const float* __restrict__ U_att,
    const float* __restrict__ b_Uatt, const float* __restrict__ fproj,
    const float* __restrict__ v_att, const float* __restrict__ b_vatt,
    float* __restrict__ alpha, float* __restrict__ alphas_out, int t) {
  const int b = blockIdx.x;
  const int tid = threadIdx.x;
  const int lane = tid & 63, w = tid >> 6;
  __shared__ float hs[Eq];
  __shared__ float vs[Eq];
  __shared__ float ah[Eq];
  __shared__ float ev[Pq];
  __shared__ float red[256];
  for (int i = tid; i < Eq; i += 256) { hs[i] = h[b * Eq + i]; vs[i] = v_att[i]; }
  __syncthreads();
  for (int e = w; e < Eq; e += 4) {
    const float* Ur = U_att + (size_t)e * Eq;
    float s = 0.f;
#pragma unroll
    for (int j = 0; j < 8; ++j) { int k = j * 64 + lane; s = fmaf(Ur[k], hs[k], s); }
#pragma unroll
    for (int off = 32; off > 0; off >>= 1) s += __shfl_xor(s, off);
    if (lane == 0) ah[e] = s + b_Uatt[e];
  }
  __syncthreads();
  const float bv = b_vatt[0];
  for (int p = w; p < Pq; p += 4) {
    const float* fp = fproj + ((size_t)b * Pq + p) * Eq;
    float s = 0.f;
#pragma unroll
    for (int j = 0; j < 8; ++j) {
      int k = j * 64 + lane;
      s = fmaf(tanhf(fp[k] + ah[k]), vs[k], s);
    }
#pragma unroll
    for (int off = 32; off > 0; off >>= 1) s += __shfl_xor(s, off);
    if (lane == 0) ev[p] = s + bv;
  }
  __syncthreads();
  float x = (tid < Pq) ? ev[tid] : -INFINITY;
  red[tid] = x;
  __syncthreads();
  for (int s = 128; s > 0; s >>= 1) {
    if (tid < s) red[tid] = fmaxf(red[tid], red[tid + s]);
    __syncthreads();
  }
  float mx = red[0];
  __syncthreads();
  float ex = (tid < Pq) ? expf(x - mx) : 0.f;
  red[tid] = ex;
  __syncthreads();
  for (int s = 128; s > 0; s >>= 1) {
    if (tid < s) red[tid] += red[tid + s];
    __syncthreads();
  }
  float inv = 1.f / red[0];
  if (tid < Pq) {
    float a = ex * inv;
    alpha[b * Pq + tid] = a;
    alphas_out[((size_t)b * Tq + t) * Pq + tid] = a;
  }
}

// ctxg[b,d] = sigmoid(sum_s Pf[s][b][d] + b_fbeta[d]) * sum_p alpha[b,p]*img[b,p,d]
// grid = (D/256, B)
__global__ __launch_bounds__(256) void context_kernel(const float* __restrict__ alpha,
                                                      const float* __restrict__ img,
                                                      const float* __restrict__ Pf,
                                                      const float* __restrict__ b_fbeta,
                                                      float* __restrict__ ctxg, int Sf) {
  const int b = blockIdx.y;
  const int d = blockIdx.x * 256 + threadIdx.x;
  __shared__ float al[Pq];
  if (threadIdx.x < Pq) al[threadIdx.x] = alpha[b * Pq + threadIdx.x];
  float gp = b_fbeta[d];
  for (int s = 0; s < Sf; ++s) gp += Pf[((size_t)s * 64 + b) * Dq + d];
  float gate = sigf(gp);
  __syncthreads();
  const float* ib = img + (size_t)b * Pq * Dq + d;
  float s = 0.f;
#pragma unroll 4
  for (int p = 0; p < Pq; ++p) s = fmaf(al[p], ib[(size_t)p * Dq], s);
  ctxg[b * Dq + d] = s * gate;
}

// Reduce gates partials + LSTM cell update. total 64*512 threads.
__global__ __launch_bounds__(256) void lstm_epilogue(const float* __restrict__ P, int S,
                                                     const float* __restrict__ b_ih,
                                                     const float* __restrict__ b_hh,
                                                     const float* __restrict__ c,
                                                     float* __restrict__ h2,
                                                     float* __restrict__ c2) {
  int idx = blockIdx.x * 256 + threadIdx.x;
  int b = idx >> 9, e = idx & 511;
  float g0 = b_ih[e] + b_hh[e];
  float g1 = b_ih[Eq + e] + b_hh[Eq + e];
  float g2 = b_ih[2 * Eq + e] + b_hh[2 * Eq + e];
  float g3 = b_ih[3 * Eq + e] + b_hh[3 * Eq + e];
  for (int s = 0; s < S; ++s) {
    const float* Pr = P + ((size_t)s * 64 + b) * 2048;
    g0 += Pr[e]; g1 += Pr[Eq + e]; g2 += Pr[2 * Eq + e]; g3 += Pr[3 * Eq + e];
  }
  float ig = sigf(g0), fg = sigf(g1), gg = tanhf(g2), og = sigf(g3);
  float cn_ = fg * c[idx] + ig * gg;
  c2[idx] = cn_;
  h2[idx] = og * tanhf(cn_);
}

}  // namespace

extern "C" void kernel_launch(void* const* d_in, const int* in_sizes, int n_in,
                              void* d_out, int out_size, void* d_ws, size_t ws_size,
                              hipStream_t stream) {
  (void)in_sizes; (void)n_in; (void)out_size; (void)ws_size;
  const float* img      = (const float*)d_in[0];
  const int*   caps     = (const int*)d_in[1];
  const float* emb      = (const float*)d_in[2];
  const float* W_init_h = (const float*)d_in[3];
  const float* b_init_h = (const float*)d_in[4];
  const float* W_init_c = (const float*)d_in[5];
  const float* b_init_c = (const float*)d_in[6];
  const float* W_fbeta  = (const float*)d_in[7];
  const float* b_fbeta  = (const float*)d_in[8];
  const float* U_att    = (const float*)d_in[9];
  const float* b_Uatt   = (const float*)d_in[10];
  const float* W_att    = (const float*)d_in[11];
  const float* b_Watt   = (const float*)d_in[12];
  const float* v_att    = (const float*)d_in[13];
  const float* b_vatt   = (const float*)d_in[14];
  const float* W_ih     = (const float*)d_in[15];
  const float* b_ih     = (const float*)d_in[16];
  const float* W_hh     = (const float*)d_in[17];
  const float* b_hh     = (const float*)d_in[18];
  const float* W_out    = (const float*)d_in[19];
  const float* b_out    = (const float*)d_in[20];

  float* out = (float*)d_out;
  float* alphas_out = out + (size_t)Bq * Tq * Vq;

  float* ws = (float*)d_ws;
  float* avg   = ws; ws += (size_t)Bq * Dq;
  float* fproj = ws; ws += (size_t)Bq * Pq * Eq;
  float* h0 = ws; ws += Bq * Eq;
  float* h1 = ws; ws += Bq * Eq;
  float* c0 = ws; ws += Bq * Eq;
  float* c1 = ws; ws += Bq * Eq;
  float* alpha = ws; ws += Bq * Pq;
  float* ctxg = ws; ws += Bq * Dq;
  float* arena = ws; ws += (size_t)2 * Bq * VqPad;  // shared split-K partial buffer (5.1 MB)

  // ---- Precompute ----
  avg_kernel<<<Bq * Dq / 256, 256, 0, stream>>>(img, avg);
  // h0 = tanh(avg @ W_init_h^T + b): N=512, K=2048, S=8 splits x 8 iters
  gemm_partial<0><<<dim3(Eq / 64, 8), 256, 0, stream>>>(avg, W_init_h, arena, Eq, Dq, 8, Eq,
                                                        nullptr, nullptr, nullptr, nullptr,
                                                        nullptr, 0);
  reduce_act_epilogue<ACT_TANH><<<Bq * Eq / 256, 256, 0, stream>>>(arena, b_init_h, h0, Eq, 8);
  gemm_partial<0><<<dim3(Eq / 64, 8), 256, 0, stream>>>(avg, W_init_c, arena, Eq, Dq, 8, Eq,
                                                        nullptr, nullptr, nullptr, nullptr,
                                                        nullptr, 0);
  reduce_act_epilogue<ACT_TANH><<<Bq * Eq / 256, 256, 0, stream>>>(arena, b_init_c, c0, Eq, 8);
  // fproj = img @ W_att^T + b_Watt : (12544, 512), K=2048 -> 1568 blocks
  gemm_tn<ACT_NONE><<<dim3(Bq * Pq / 64, Eq / 64), 256, 0, stream>>>(img, W_att, b_Watt, fproj,
                                                                     Bq * Pq, Eq, Dq);

  float* hc = h0; float* cc_ = c0; float* hn = h1; float* cn = c1;
  for (int t = 0; t < Tq; ++t) {
    attention_kernel<<<Bq, 256, 0, stream>>>(hc, U_att, b_Uatt, fproj, v_att, b_vatt, alpha,
                                             alphas_out, t);
    // fbeta partials: N=2048, K=512, S=4 x 4 iters -> 128 blocks
    gemm_partial<0><<<dim3(Dq / 64, 4), 256, 0, stream>>>(hc, W_fbeta, arena, Dq, Eq, 4, Dq,
                                                          nullptr, nullptr, nullptr, nullptr,
                                                          nullptr, 0);
    context_kernel<<<dim3(Dq / 256, Bq), 256, 0, stream>>>(alpha, img, arena, b_fbeta, ctxg, 4);
    // gates partials: N=2048, K=3072, S=8 x 12 iters -> 256 blocks
    gemm_partial<1><<<dim3(Dq / 64, 8), 256, 0, stream>>>(nullptr, W_ih, arena, Dq, 0, 12, Dq,
                                                          emb, caps, ctxg, hc, W_hh, t);
    lstm_epilogue<<<Bq * Eq / 256, 256, 0, stream>>>(arena, 8, b_ih, b_hh, cc_, hn, cn);
    // out partials: N=10000 (pad 10048), K=512, S=2 x 8 iters -> 314 blocks
    gemm_partial<0><<<dim3(VqPad / 64, 2), 256, 0, stream>>>(hn, W_out, arena, Vq, Eq, 8, VqPad,
                                                             nullptr, nullptr, nullptr, nullptr,
                                                             nullptr, 0);
    out_epilogue<<<dim3(40, Bq), 256, 0, stream>>>(arena, b_out, out, t);
    float* tmp = hc; hc = hn; hn = tmp;
    tmp = cc_; cc_ = cn; cn = tmp;
  }
}

// Round 3
// 8414.065 us; speedup vs baseline: 4.4835x; 1.3310x over previous
//
#include <hip/hip_runtime.h>
#include <math.h>

namespace {

constexpr int Bq = 64, Pq = 196, Dq = 2048, Eq = 512, Vq = 10000, Tq = 32, T1q = 33;
constexpr int VqPad = 10048;  // 157*64

enum Act { ACT_NONE = 0, ACT_TANH = 1, ACT_SIG = 2 };

__device__ __forceinline__ float sigf(float x) { return 1.f / (1.f + expf(-x)); }

// ---------------- one-time kernels ----------------

// C = act(A @ W^T + bias). Used for the big one-time feat_proj GEMM.
template <int ACT>
__global__ __launch_bounds__(256) void gemm_tn(const float* __restrict__ A,
                                               const float* __restrict__ W,
                                               const float* __restrict__ bias,
                                               float* __restrict__ C,
                                               int M, int N, int K) {
  __shared__ float As[32][66];
  __shared__ float Ws[32][66];
  const int tid = threadIdx.x;
  const int tx = tid & 15, ty = tid >> 4;
  const int m0 = blockIdx.x * 64, n0 = blockIdx.y * 64;
  float acc[4][4] = {};
  for (int k0 = 0; k0 < K; k0 += 32) {
#pragma unroll
    for (int i = 0; i < 2; ++i) {
      int idx = tid + i * 256;
      int r = idx >> 3, c = (idx & 7) << 2;
      const float4 a = *reinterpret_cast<const float4*>(A + (size_t)(m0 + r) * K + k0 + c);
      As[c + 0][r] = a.x; As[c + 1][r] = a.y; As[c + 2][r] = a.z; As[c + 3][r] = a.w;
      const float4 w = *reinterpret_cast<const float4*>(W + (size_t)(n0 + r) * K + k0 + c);
      Ws[c + 0][r] = w.x; Ws[c + 1][r] = w.y; Ws[c + 2][r] = w.z; Ws[c + 3][r] = w.w;
    }
    __syncthreads();
#pragma unroll
    for (int k = 0; k < 32; ++k) {
      float a[4], w[4];
#pragma unroll
      for (int i = 0; i < 4; ++i) { a[i] = As[k][ty * 4 + i]; w[i] = Ws[k][tx * 4 + i]; }
#pragma unroll
      for (int mi = 0; mi < 4; ++mi)
#pragma unroll
        for (int ni = 0; ni < 4; ++ni) acc[mi][ni] = fmaf(a[mi], w[ni], acc[mi][ni]);
    }
    __syncthreads();
  }
#pragma unroll
  for (int ni = 0; ni < 4; ++ni) {
    int n = n0 + tx * 4 + ni;
    float bv = bias ? bias[n] : 0.f;
#pragma unroll
    for (int mi = 0; mi < 4; ++mi) {
      float v = acc[mi][ni] + bv;
      if (ACT == ACT_TANH) v = tanhf(v);
      else if (ACT == ACT_SIG) v = sigf(v);
      C[(size_t)(m0 + ty * 4 + mi) * N + n] = v;
    }
  }
}

// Split-K partial GEMM (M=64). MODE 0: plain A. MODE 1: A = [emb_t|ctxg|h], W = [W_ih|W_hh].
template <int MODE>
__global__ __launch_bounds__(256) void gemm_partial(
    const float* __restrict__ A, const float* __restrict__ W,
    float* __restrict__ P, int N, int ldW, int iters, int Npad,
    const float* __restrict__ emb, const int* __restrict__ caps,
    const float* __restrict__ ctxg, const float* __restrict__ h,
    const float* __restrict__ W2, int t) {
  __shared__ float As[32][66];
  __shared__ float Ws[32][66];
  const int tid = threadIdx.x;
  const int tx = tid & 15, ty = tid >> 4;
  const int n0 = blockIdx.x * 64;
  const int split = blockIdx.y;
  const int kbeg = split * iters * 32;
  float acc[4][4] = {};
  for (int it = 0; it < iters; ++it) {
    const int k0 = kbeg + it * 32;
#pragma unroll
    for (int i = 0; i < 2; ++i) {
      int idx = tid + i * 256;
      int r = idx >> 3, c = (idx & 7) << 2;
      float4 a;
      if (MODE == 0) {
        a = *reinterpret_cast<const float4*>(A + (size_t)r * ldW + k0 + c);
      } else {
        int k = k0 + c;
        if (k0 < Eq) {
          int tok = caps[r * T1q + t];
          a = *reinterpret_cast<const float4*>(emb + (size_t)tok * Eq + k);
        } else if (k0 < Eq + Dq) {
          a = *reinterpret_cast<const float4*>(ctxg + (size_t)r * Dq + (k - Eq));
        } else {
          a = *reinterpret_cast<const float4*>(h + (size_t)r * Eq + (k - Eq - Dq));
        }
      }
      As[c + 0][r] = a.x; As[c + 1][r] = a.y; As[c + 2][r] = a.z; As[c + 3][r] = a.w;
      int wr = n0 + r; if (wr >= N) wr = N - 1;
      float4 w;
      if (MODE == 0) {
        w = *reinterpret_cast<const float4*>(W + (size_t)wr * ldW + k0 + c);
      } else {
        int k = k0 + c;
        if (k0 < Eq + Dq) w = *reinterpret_cast<const float4*>(W + (size_t)wr * (Eq + Dq) + k);
        else w = *reinterpret_cast<const float4*>(W2 + (size_t)wr * Eq + (k - Eq - Dq));
      }
      Ws[c + 0][r] = w.x; Ws[c + 1][r] = w.y; Ws[c + 2][r] = w.z; Ws[c + 3][r] = w.w;
    }
    __syncthreads();
#pragma unroll
    for (int k = 0; k < 32; ++k) {
      float a[4], w[4];
#pragma unroll
      for (int i = 0; i < 4; ++i) { a[i] = As[k][ty * 4 + i]; w[i] = Ws[k][tx * 4 + i]; }
#pragma unroll
      for (int mi = 0; mi < 4; ++mi)
#pragma unroll
        for (int ni = 0; ni < 4; ++ni) acc[mi][ni] = fmaf(a[mi], w[ni], acc[mi][ni]);
    }
    __syncthreads();
  }
  float* Pb = P + (size_t)split * 64 * Npad;
#pragma unroll
  for (int ni = 0; ni < 4; ++ni) {
    int n = n0 + tx * 4 + ni;
#pragma unroll
    for (int mi = 0; mi < 4; ++mi) Pb[(size_t)(ty * 4 + mi) * Npad + n] = acc[mi][ni];
  }
}

template <int ACT>
__global__ __launch_bounds__(256) void reduce_act_epilogue(const float* __restrict__ P,
                                                           const float* __restrict__ bias,
                                                           float* __restrict__ C, int N,
                                                           int S) {
  int idx = blockIdx.x * 256 + threadIdx.x;
  int b = idx / N, n = idx - b * N;
  float s = bias[n];
  for (int i = 0; i < S; ++i) s += P[((size_t)i * 64 + b) * N + n];
  if (ACT == ACT_TANH) s = tanhf(s);
  else if (ACT == ACT_SIG) s = sigf(s);
  C[(size_t)b * N + n] = s;
}

// avg[b,d] = mean_p img[b,p,d]; grid = B*D/256
__global__ __launch_bounds__(256) void avg_kernel(const float* __restrict__ img,
                                                  float* __restrict__ avg) {
  int idx = blockIdx.x * 256 + threadIdx.x;
  int b = idx >> 11, d = idx & (Dq - 1);
  const float* ib = img + (size_t)b * Pq * Dq + d;
  float s = 0.f;
  for (int p = 0; p < Pq; ++p) s += ib[(size_t)p * Dq];
  avg[idx] = s * (1.f / Pq);
}

// Batched output GEMM over all timesteps: hseq(2048,512) @ W_out(10000,512)^T + b_out.
// hseq row m = t*64 + b; out row = b*T + t. grid (32, 157).
__global__ __launch_bounds__(256) void gemm_out_final(const float* __restrict__ hseq,
                                                      const float* __restrict__ W_out,
                                                      const float* __restrict__ b_out,
                                                      float* __restrict__ out) {
  __shared__ float As[32][66];
  __shared__ float Ws[32][66];
  const int tid = threadIdx.x;
  const int tx = tid & 15, ty = tid >> 4;
  const int m0 = blockIdx.x * 64, n0 = blockIdx.y * 64;
  float acc[4][4] = {};
  for (int k0 = 0; k0 < Eq; k0 += 32) {
#pragma unroll
    for (int i = 0; i < 2; ++i) {
      int idx = tid + i * 256;
      int r = idx >> 3, c = (idx & 7) << 2;
      const float4 a = *reinterpret_cast<const float4*>(hseq + (size_t)(m0 + r) * Eq + k0 + c);
      As[c + 0][r] = a.x; As[c + 1][r] = a.y; As[c + 2][r] = a.z; As[c + 3][r] = a.w;
      int wr = n0 + r; if (wr >= Vq) wr = Vq - 1;
      const float4 w = *reinterpret_cast<const float4*>(W_out + (size_t)wr * Eq + k0 + c);
      Ws[c + 0][r] = w.x; Ws[c + 1][r] = w.y; Ws[c + 2][r] = w.z; Ws[c + 3][r] = w.w;
    }
    __syncthreads();
#pragma unroll
    for (int k = 0; k < 32; ++k) {
      float a[4], w[4];
#pragma unroll
      for (int i = 0; i < 4; ++i) { a[i] = As[k][ty * 4 + i]; w[i] = Ws[k][tx * 4 + i]; }
#pragma unroll
      for (int mi = 0; mi < 4; ++mi)
#pragma unroll
        for (int ni = 0; ni < 4; ++ni) acc[mi][ni] = fmaf(a[mi], w[ni], acc[mi][ni]);
    }
    __syncthreads();
  }
#pragma unroll
  for (int ni = 0; ni < 4; ++ni) {
    int n = n0 + tx * 4 + ni;
    if (n < Vq) {
      float bv = b_out[n];
#pragma unroll
      for (int mi = 0; mi < 4; ++mi) {
        int m = m0 + ty * 4 + mi;
        int t = m >> 6, b = m & 63;
        out[((size_t)b * Tq + t) * Vq + n] = acc[mi][ni] + bv;
      }
    }
  }
}

// ---------------- per-step kernels ----------------

// K1: att_h partials (blocks 0..31) + fbeta partials (blocks 32..159). A = h, K = 512 both.
__global__ __launch_bounds__(256) void prestep_kernel(const float* __restrict__ h,
                                                      const float* __restrict__ U_att,
                                                      const float* __restrict__ W_fbeta,
                                                      float* __restrict__ Pah,
                                                      float* __restrict__ Pfb) {
  __shared__ float As[32][66];
  __shared__ float Ws[32][66];
  const int bx = blockIdx.x;
  const float* W; float* P; int n0, kbeg, Npad;
  if (bx < 32) {
    W = U_att; P = Pah + (size_t)(bx >> 3) * 64 * Eq; n0 = (bx & 7) * 64;
    kbeg = (bx >> 3) * 128; Npad = Eq;
  } else {
    int idx = bx - 32;
    W = W_fbeta; P = Pfb + (size_t)(idx >> 5) * 64 * Dq; n0 = (idx & 31) * 64;
    kbeg = (idx >> 5) * 128; Npad = Dq;
  }
  const int tid = threadIdx.x;
  const int tx = tid & 15, ty = tid >> 4;
  float acc[4][4] = {};
  for (int it = 0; it < 4; ++it) {
    const int k0 = kbeg + it * 32;
#pragma unroll
    for (int i = 0; i < 2; ++i) {
      int idx = tid + i * 256;
      int r = idx >> 3, c = (idx & 7) << 2;
      const float4 a = *reinterpret_cast<const float4*>(h + (size_t)r * Eq + k0 + c);
      As[c + 0][r] = a.x; As[c + 1][r] = a.y; As[c + 2][r] = a.z; As[c + 3][r] = a.w;
      const float4 w = *reinterpret_cast<const float4*>(W + (size_t)(n0 + r) * Eq + k0 + c);
      Ws[c + 0][r] = w.x; Ws[c + 1][r] = w.y; Ws[c + 2][r] = w.z; Ws[c + 3][r] = w.w;
    }
    __syncthreads();
#pragma unroll
    for (int k = 0; k < 32; ++k) {
      float a[4], w[4];
#pragma unroll
      for (int i = 0; i < 4; ++i) { a[i] = As[k][ty * 4 + i]; w[i] = Ws[k][tx * 4 + i]; }
#pragma unroll
      for (int mi = 0; mi < 4; ++mi)
#pragma unroll
        for (int ni = 0; ni < 4; ++ni) acc[mi][ni] = fmaf(a[mi], w[ni], acc[mi][ni]);
    }
    __syncthreads();
  }
#pragma unroll
  for (int ni = 0; ni < 4; ++ni) {
    int n = n0 + tx * 4 + ni;
#pragma unroll
    for (int mi = 0; mi < 4; ++mi) P[(size_t)(ty * 4 + mi) * Npad + n] = acc[mi][ni];
  }
}

// K2: e + softmax + gated context, fused. grid (B, 4 d-slices), block 256.
__global__ __launch_bounds__(256) void att_ctx_kernel(
    const float* __restrict__ Pah, const float* __restrict__ b_Uatt,
    const float* __restrict__ fproj, const float* __restrict__ v_att,
    const float* __restrict__ b_vatt, const float* __restrict__ Pfb,
    const float* __restrict__ b_fbeta, const float* __restrict__ img,
    float* __restrict__ ctxg, float* __restrict__ alphas_out, int t) {
  const int b = blockIdx.x;
  const int tid = threadIdx.x;
  const int lane = tid & 63, w = tid >> 6;
  __shared__ float ah[Eq];
  __shared__ float vs[Eq];
  __shared__ float ev[256];
  __shared__ float al[256];
  __shared__ float red[256];
  for (int i = tid; i < Eq; i += 256) {
    float s = b_Uatt[i];
#pragma unroll
    for (int sp = 0; sp < 4; ++sp) s += Pah[((size_t)sp * 64 + b) * Eq + i];
    ah[i] = s;
    vs[i] = v_att[i];
  }
  __syncthreads();
  const float bv = b_vatt[0];
  for (int p = w; p < Pq; p += 4) {
    const float* fp = fproj + ((size_t)b * Pq + p) * Eq;
    float s = 0.f;
#pragma unroll
    for (int j = 0; j < 8; ++j) {
      int k = j * 64 + lane;
      s = fmaf(tanhf(fp[k] + ah[k]), vs[k], s);
    }
#pragma unroll
    for (int off = 32; off > 0; off >>= 1) s += __shfl_xor(s, off);
    if (lane == 0) ev[p] = s + bv;
  }
  __syncthreads();
  float x = (tid < Pq) ? ev[tid] : -INFINITY;
  red[tid] = x;
  __syncthreads();
  for (int s = 128; s > 0; s >>= 1) {
    if (tid < s) red[tid] = fmaxf(red[tid], red[tid + s]);
    __syncthreads();
  }
  float mx = red[0];
  __syncthreads();
  float ex = (tid < Pq) ? expf(x - mx) : 0.f;
  red[tid] = ex;
  __syncthreads();
  for (int s = 128; s > 0; s >>= 1) {
    if (tid < s) red[tid] += red[tid + s];
    __syncthreads();
  }
  float inv = 1.f / red[0];
  if (tid < Pq) {
    float a = ex * inv;
    al[tid] = a;
    if (blockIdx.y == 0) alphas_out[((size_t)b * Tq + t) * Pq + tid] = a;
  }
  __syncthreads();
  // gated context for this block's 512-d slice
  const int d0 = blockIdx.y * 512 + tid;
  const float* ib = img + (size_t)b * Pq * Dq + d0;
  float s0 = 0.f, s1 = 0.f;
#pragma unroll 2
  for (int p = 0; p < Pq; ++p) {
    float a = al[p];
    const float* r = ib + (size_t)p * Dq;
    s0 = fmaf(a, r[0], s0);
    s1 = fmaf(a, r[256], s1);
  }
  float gp0 = b_fbeta[d0], gp1 = b_fbeta[d0 + 256];
#pragma unroll
  for (int sp = 0; sp < 4; ++sp) {
    const float* Pr = Pfb + ((size_t)sp * 64 + b) * Dq;
    gp0 += Pr[d0]; gp1 += Pr[d0 + 256];
  }
  ctxg[(size_t)b * Dq + d0] = s0 * sigf(gp0);
  ctxg[(size_t)b * Dq + d0 + 256] = s1 * sigf(gp1);
}

// K4: reduce gates partials + LSTM cell update; h2 -> hseq slot t.
__global__ __launch_bounds__(256) void lstm_epilogue(const float* __restrict__ P, int S,
                                                     const float* __restrict__ b_ih,
                                                     const float* __restrict__ b_hh,
                                                     const float* __restrict__ c,
                                                     float* __restrict__ h2,
                                                     float* __restrict__ c2) {
  int idx = blockIdx.x * 256 + threadIdx.x;
  int b = idx >> 9, e = idx & 511;
  float g0 = b_ih[e] + b_hh[e];
  float g1 = b_ih[Eq + e] + b_hh[Eq + e];
  float g2 = b_ih[2 * Eq + e] + b_hh[2 * Eq + e];
  float g3 = b_ih[3 * Eq + e] + b_hh[3 * Eq + e];
  for (int s = 0; s < S; ++s) {
    const float* Pr = P + ((size_t)s * 64 + b) * 2048;
    g0 += Pr[e]; g1 += Pr[Eq + e]; g2 += Pr[2 * Eq + e]; g3 += Pr[3 * Eq + e];
  }
  float ig = sigf(g0), fg = sigf(g1), gg = tanhf(g2), og = sigf(g3);
  float cn_ = fg * c[idx] + ig * gg;
  c2[idx] = cn_;
  h2[idx] = og * tanhf(cn_);
}

}  // namespace

extern "C" void kernel_launch(void* const* d_in, const int* in_sizes, int n_in,
                              void* d_out, int out_size, void* d_ws, size_t ws_size,
                              hipStream_t stream) {
  (void)in_sizes; (void)n_in; (void)out_size; (void)ws_size;
  const float* img      = (const float*)d_in[0];
  const int*   caps     = (const int*)d_in[1];
  const float* emb      = (const float*)d_in[2];
  const float* W_init_h = (const float*)d_in[3];
  const float* b_init_h = (const float*)d_in[4];
  const float* W_init_c = (const float*)d_in[5];
  const float* b_init_c = (const float*)d_in[6];
  const float* W_fbeta  = (const float*)d_in[7];
  const float* b_fbeta  = (const float*)d_in[8];
  const float* U_att    = (const float*)d_in[9];
  const float* b_Uatt   = (const float*)d_in[10];
  const float* W_att    = (const float*)d_in[11];
  const float* b_Watt   = (const float*)d_in[12];
  const float* v_att    = (const float*)d_in[13];
  const float* b_vatt   = (const float*)d_in[14];
  const float* W_ih     = (const float*)d_in[15];
  const float* b_ih     = (const float*)d_in[16];
  const float* W_hh     = (const float*)d_in[17];
  const float* b_hh     = (const float*)d_in[18];
  const float* W_out    = (const float*)d_in[19];
  const float* b_out    = (const float*)d_in[20];

  float* out = (float*)d_out;
  float* alphas_out = out + (size_t)Bq * Tq * Vq;

  float* ws = (float*)d_ws;
  float* fproj = ws; ws += (size_t)Bq * Pq * Eq;        // 6422528
  float* hseq  = ws; ws += (size_t)Tq * Bq * Eq;        // 1048576
  float* h0    = ws; ws += Bq * Eq;
  float* c0    = ws; ws += Bq * Eq;
  float* c1    = ws; ws += Bq * Eq;
  float* ctxg  = ws; ws += Bq * Dq;
  float* buf   = ws; ws += (size_t)8 * Bq * Dq;         // 1048576 shared partial arena
  float* Pah = buf;                    // 4*64*512   (K1/K2 window)
  float* Pfb = buf + 4 * Bq * Eq;      // 4*64*2048
  float* Pg  = buf;                    // 8*64*2048  (K3/K4 window)
  float* initP = buf;                  // 8*64*512   (init window)
  float* avg = buf + 8 * Bq * Eq;      // 64*2048    (init window)

  // ---- Precompute ----
  avg_kernel<<<Bq * Dq / 256, 256, 0, stream>>>(img, avg);
  gemm_partial<0><<<dim3(Eq / 64, 8), 256, 0, stream>>>(avg, W_init_h, initP, Eq, Dq, 8, Eq,
                                                        nullptr, nullptr, nullptr, nullptr,
                                                        nullptr, 0);
  reduce_act_epilogue<ACT_TANH><<<Bq * Eq / 256, 256, 0, stream>>>(initP, b_init_h, h0, Eq, 8);
  gemm_partial<0><<<dim3(Eq / 64, 8), 256, 0, stream>>>(avg, W_init_c, initP, Eq, Dq, 8, Eq,
                                                        nullptr, nullptr, nullptr, nullptr,
                                                        nullptr, 0);
  reduce_act_epilogue<ACT_TANH><<<Bq * Eq / 256, 256, 0, stream>>>(initP, b_init_c, c0, Eq, 8);
  gemm_tn<ACT_NONE><<<dim3(Bq * Pq / 64, Eq / 64), 256, 0, stream>>>(img, W_att, b_Watt, fproj,
                                                                     Bq * Pq, Eq, Dq);

  float* cc_ = c0; float* cn = c1;
  const float* hc = h0;
  for (int t = 0; t < Tq; ++t) {
    prestep_kernel<<<160, 256, 0, stream>>>(hc, U_att, W_fbeta, Pah, Pfb);
    att_ctx_kernel<<<dim3(Bq, 4), 256, 0, stream>>>(Pah, b_Uatt, fproj, v_att, b_vatt, Pfb,
                                                    b_fbeta, img, ctxg, alphas_out, t);
    gemm_partial<1><<<dim3(Dq / 64, 8), 256, 0, stream>>>(nullptr, W_ih, Pg, Dq, 0, 12, Dq,
                                                          emb, caps, ctxg, hc, W_hh, t);
    float* hn = hseq + (size_t)t * Bq * Eq;
    lstm_epilogue<<<Bq * Eq / 256, 256, 0, stream>>>(Pg, 8, b_ih, b_hh, cc_, hn, cn);
    hc = hn;
    float* tmp = cc_; cc_ = cn; cn = tmp;
  }
  // Batched preds GEMM over all 32 steps
  gemm_out_final<<<dim3(Tq * Bq / 64, VqPad / 64), 256, 0, stream>>>(hseq, W_out, b_out, out);
}

// Round 4
// 7950.520 us; speedup vs baseline: 4.7449x; 1.0583x over previous
//
#include <hip/hip_runtime.h>
#include <math.h>

namespace {

constexpr int Bq = 64, Pq = 196, Dq = 2048, Eq = 512, Vq = 10000, Tq = 32, T1q = 33;

enum Act { ACT_NONE = 0, ACT_TANH = 1, ACT_SIG = 2 };

typedef __attribute__((ext_vector_type(8))) short bf16x8;
typedef __attribute__((ext_vector_type(4))) float f32x4;

__device__ __forceinline__ float sigf(float x) { return 1.f / (1.f + expf(-x)); }

__device__ __forceinline__ ushort f2bf(float f) {
  union { float f; unsigned u; } v; v.f = f;
  unsigned u = v.u;
  return (ushort)((u + 0x7fffu + ((u >> 16) & 1u)) >> 16);  // RNE
}
__device__ __forceinline__ float bf2f(ushort h) {
  union { unsigned u; float f; } v; v.u = ((unsigned)h) << 16;
  return v.f;
}

// fp32 -> bf16, 8 elems/thread. n8 = n/8.
__global__ __launch_bounds__(256) void cvt_bf16(const float* __restrict__ in,
                                                ushort* __restrict__ out, int n8) {
  int i = blockIdx.x * 256 + threadIdx.x;
  if (i >= n8) return;
  const float4 a = reinterpret_cast<const float4*>(in)[2 * i];
  const float4 b = reinterpret_cast<const float4*>(in)[2 * i + 1];
  union { ushort s[8]; uint4 v; } o;
  o.s[0] = f2bf(a.x); o.s[1] = f2bf(a.y); o.s[2] = f2bf(a.z); o.s[3] = f2bf(a.w);
  o.s[4] = f2bf(b.x); o.s[5] = f2bf(b.y); o.s[6] = f2bf(b.z); o.s[7] = f2bf(b.w);
  reinterpret_cast<uint4*>(out)[i] = o.v;
}

// ---------------- one-time: fproj via bf16 MFMA ----------------
// C(M=12544, N=512) = A16 @ B16^T + bias. BM=128 BN=64 BK=32. grid (98, 8).
__global__ __launch_bounds__(256) void fproj_mfma(const ushort* __restrict__ A16,
                                                  const ushort* __restrict__ B16,
                                                  const float* __restrict__ bias,
                                                  float* __restrict__ C) {
  __shared__ ushort As[128 * 32];
  __shared__ ushort Bs[64 * 32];
  const int tid = threadIdx.x;
  const int lane = tid & 63, wave = tid >> 6;
  const int m0 = blockIdx.x * 128, n0 = blockIdx.y * 64;
  const int wr = (wave >> 1) * 64, wc = (wave & 1) * 32;
  f32x4 acc[4][2] = {};
  const int ar = tid >> 1, seg = (tid & 1) * 16;
  const int br = (tid & 127) >> 1;
  for (int k0 = 0; k0 < Dq; k0 += 32) {
    const ushort* ga = A16 + (size_t)(m0 + ar) * Dq + k0 + seg;
    uint4 a0 = *reinterpret_cast<const uint4*>(ga);
    uint4 a1 = *reinterpret_cast<const uint4*>(ga + 8);
    unsigned ab = (unsigned)(ar * 64 + seg * 2);
    unsigned sw = (unsigned)((ar & 7) << 4);
    *reinterpret_cast<uint4*>(reinterpret_cast<char*>(As) + (ab ^ sw)) = a0;
    *reinterpret_cast<uint4*>(reinterpret_cast<char*>(As) + ((ab + 16) ^ sw)) = a1;
    if (tid < 128) {
      const ushort* gb = B16 + (size_t)(n0 + br) * Dq + k0 + seg;
      uint4 b0 = *reinterpret_cast<const uint4*>(gb);
      uint4 b1 = *reinterpret_cast<const uint4*>(gb + 8);
      unsigned bb = (unsigned)(br * 64 + seg * 2);
      unsigned sb = (unsigned)((br & 7) << 4);
      *reinterpret_cast<uint4*>(reinterpret_cast<char*>(Bs) + (bb ^ sb)) = b0;
      *reinterpret_cast<uint4*>(reinterpret_cast<char*>(Bs) + ((bb + 16) ^ sb)) = b1;
    }
    __syncthreads();
    const int g = lane >> 4;
    bf16x8 af[4], bfr[2];
#pragma unroll
    for (int i = 0; i < 4; ++i) {
      int row = wr + i * 16 + (lane & 15);
      af[i] = *reinterpret_cast<const bf16x8*>(
          reinterpret_cast<char*>(As) + ((unsigned)(row * 64 + g * 16) ^ ((row & 7) << 4)));
    }
#pragma unroll
    for (int j = 0; j < 2; ++j) {
      int col = wc + j * 16 + (lane & 15);
      bfr[j] = *reinterpret_cast<const bf16x8*>(
          reinterpret_cast<char*>(Bs) + ((unsigned)(col * 64 + g * 16) ^ ((col & 7) << 4)));
    }
#pragma unroll
    for (int i = 0; i < 4; ++i)
#pragma unroll
      for (int j = 0; j < 2; ++j)
        acc[i][j] = __builtin_amdgcn_mfma_f32_16x16x32_bf16(af[i], bfr[j], acc[i][j], 0, 0, 0);
    __syncthreads();
  }
#pragma unroll
  for (int i = 0; i < 4; ++i) {
#pragma unroll
    for (int j = 0; j < 2; ++j) {
      int n = n0 + wc + j * 16 + (lane & 15);
      float bv = bias[n];
#pragma unroll
      for (int q = 0; q < 4; ++q) {
        int m = m0 + wr + i * 16 + (lane >> 4) * 4 + q;
        C[(size_t)m * Eq + n] = acc[i][j][q] + bv;
      }
    }
  }
}

// ---------------- split-K partial GEMM (M=64) ----------------
template <int MODE>
__global__ __launch_bounds__(256) void gemm_partial(
    const float* __restrict__ A, const float* __restrict__ W,
    float* __restrict__ P, int N, int ldW, int iters, int Npad,
    const float* __restrict__ emb, const int* __restrict__ caps,
    const float* __restrict__ ctxg, const float* __restrict__ h,
    const float* __restrict__ W2, int t) {
  __shared__ float As[32][66];
  __shared__ float Ws[32][66];
  const int tid = threadIdx.x;
  const int tx = tid & 15, ty = tid >> 4;
  const int n0 = blockIdx.x * 64;
  const int split = blockIdx.y;
  const int kbeg = split * iters * 32;
  float acc[4][4] = {};
  for (int it = 0; it < iters; ++it) {
    const int k0 = kbeg + it * 32;
#pragma unroll
    for (int i = 0; i < 2; ++i) {
      int idx = tid + i * 256;
      int r = idx >> 3, c = (idx & 7) << 2;
      float4 a;
      if (MODE == 0) {
        a = *reinterpret_cast<const float4*>(A + (size_t)r * ldW + k0 + c);
      } else {
        int k = k0 + c;
        if (k0 < Eq) {
          int tok = caps[r * T1q + t];
          a = *reinterpret_cast<const float4*>(emb + (size_t)tok * Eq + k);
        } else if (k0 < Eq + Dq) {
          a = *reinterpret_cast<const float4*>(ctxg + (size_t)r * Dq + (k - Eq));
        } else {
          a = *reinterpret_cast<const float4*>(h + (size_t)r * Eq + (k - Eq - Dq));
        }
      }
      As[c + 0][r] = a.x; As[c + 1][r] = a.y; As[c + 2][r] = a.z; As[c + 3][r] = a.w;
      int wr = n0 + r; if (wr >= N) wr = N - 1;
      float4 w;
      if (MODE == 0) {
        w = *reinterpret_cast<const float4*>(W + (size_t)wr * ldW + k0 + c);
      } else {
        int k = k0 + c;
        if (k0 < Eq + Dq) w = *reinterpret_cast<const float4*>(W + (size_t)wr * (Eq + Dq) + k);
        else w = *reinterpret_cast<const float4*>(W2 + (size_t)wr * Eq + (k - Eq - Dq));
      }
      Ws[c + 0][r] = w.x; Ws[c + 1][r] = w.y; Ws[c + 2][r] = w.z; Ws[c + 3][r] = w.w;
    }
    __syncthreads();
#pragma unroll
    for (int k = 0; k < 32; ++k) {
      float a[4], w[4];
#pragma unroll
      for (int i = 0; i < 4; ++i) { a[i] = As[k][ty * 4 + i]; w[i] = Ws[k][tx * 4 + i]; }
#pragma unroll
      for (int mi = 0; mi < 4; ++mi)
#pragma unroll
        for (int ni = 0; ni < 4; ++ni) acc[mi][ni] = fmaf(a[mi], w[ni], acc[mi][ni]);
    }
    __syncthreads();
  }
  float* Pb = P + (size_t)split * 64 * Npad;
#pragma unroll
  for (int ni = 0; ni < 4; ++ni) {
    int n = n0 + tx * 4 + ni;
#pragma unroll
    for (int mi = 0; mi < 4; ++mi) Pb[(size_t)(ty * 4 + mi) * Npad + n] = acc[mi][ni];
  }
}

template <int ACT>
__global__ __launch_bounds__(256) void reduce_act_epilogue(const float* __restrict__ P,
                                                           const float* __restrict__ bias,
                                                           float* __restrict__ C, int N,
                                                           int S) {
  int idx = blockIdx.x * 256 + threadIdx.x;
  int b = idx / N, n = idx - b * N;
  float s = bias[n];
  for (int i = 0; i < S; ++i) s += P[((size_t)i * 64 + b) * N + n];
  if (ACT == ACT_TANH) s = tanhf(s);
  else if (ACT == ACT_SIG) s = sigf(s);
  C[(size_t)b * N + n] = s;
}

__global__ __launch_bounds__(256) void avg_kernel(const float* __restrict__ img,
                                                  float* __restrict__ avg) {
  int idx = blockIdx.x * 256 + threadIdx.x;
  int b = idx >> 11, d = idx & (Dq - 1);
  const float* ib = img + (size_t)b * Pq * Dq + d;
  float s = 0.f;
  for (int p = 0; p < Pq; ++p) s += ib[(size_t)p * Dq];
  avg[idx] = s * (1.f / Pq);
}

// Batched preds GEMM: hseq(2048,512) @ W_out(10000,512)^T + b_out. BM=128 BN=64.
// grid (16, 157). hseq row m = t*64+b; out row = b*T+t.
__global__ __launch_bounds__(256) void gemm_out_big(const float* __restrict__ hseq,
                                                    const float* __restrict__ W_out,
                                                    const float* __restrict__ b_out,
                                                    float* __restrict__ out) {
  __shared__ float As[32][132];
  __shared__ float Ws[32][68];
  const int tid = threadIdx.x;
  const int tx = tid & 15, ty = tid >> 4;
  const int m0 = blockIdx.x * 128, n0 = blockIdx.y * 64;
  float acc[8][4] = {};
  for (int k0 = 0; k0 < Eq; k0 += 32) {
#pragma unroll
    for (int i = 0; i < 4; ++i) {
      int idx = tid + i * 256;
      int r = idx >> 3, c = (idx & 7) << 2;
      const float4 a = *reinterpret_cast<const float4*>(hseq + (size_t)(m0 + r) * Eq + k0 + c);
      As[c + 0][r] = a.x; As[c + 1][r] = a.y; As[c + 2][r] = a.z; As[c + 3][r] = a.w;
    }
#pragma unroll
    for (int i = 0; i < 2; ++i) {
      int idx = tid + i * 256;
      int r = idx >> 3, c = (idx & 7) << 2;
      int wr2 = n0 + r; if (wr2 >= Vq) wr2 = Vq - 1;
      const float4 w = *reinterpret_cast<const float4*>(W_out + (size_t)wr2 * Eq + k0 + c);
      Ws[c + 0][r] = w.x; Ws[c + 1][r] = w.y; Ws[c + 2][r] = w.z; Ws[c + 3][r] = w.w;
    }
    __syncthreads();
#pragma unroll
    for (int k = 0; k < 32; ++k) {
      float a[8], w[4];
#pragma unroll
      for (int i = 0; i < 8; ++i) a[i] = As[k][ty * 8 + i];
#pragma unroll
      for (int j = 0; j < 4; ++j) w[j] = Ws[k][tx * 4 + j];
#pragma unroll
      for (int i = 0; i < 8; ++i)
#pragma unroll
        for (int j = 0; j < 4; ++j) acc[i][j] = fmaf(a[i], w[j], acc[i][j]);
    }
    __syncthreads();
  }
#pragma unroll
  for (int j = 0; j < 4; ++j) {
    int n = n0 + tx * 4 + j;
    if (n < Vq) {
      float bv = b_out[n];
#pragma unroll
      for (int i = 0; i < 8; ++i) {
        int m = m0 + ty * 8 + i;
        int t = m >> 6, b = m & 63;
        out[((size_t)b * Tq + t) * Vq + n] = acc[i][j] + bv;
      }
    }
  }
}

// ---------------- per-step kernels ----------------

// K1: att_h partials (blocks 0..31) + fbeta partials (blocks 32..159). K=512 both.
__global__ __launch_bounds__(256) void prestep_kernel(const float* __restrict__ h,
                                                      const float* __restrict__ U_att,
                                                      const float* __restrict__ W_fbeta,
                                                      float* __restrict__ Pah,
                                                      float* __restrict__ Pfb) {
  __shared__ float As[32][66];
  __shared__ float Ws[32][66];
  const int bx = blockIdx.x;
  const float* W; float* P; int n0, kbeg, Npad;
  if (bx < 32) {
    W = U_att; P = Pah + (size_t)(bx >> 3) * 64 * Eq; n0 = (bx & 7) * 64;
    kbeg = (bx >> 3) * 128; Npad = Eq;
  } else {
    int idx = bx - 32;
    W = W_fbeta; P = Pfb + (size_t)(idx >> 5) * 64 * Dq; n0 = (idx & 31) * 64;
    kbeg = (idx >> 5) * 128; Npad = Dq;
  }
  const int tid = threadIdx.x;
  const int tx = tid & 15, ty = tid >> 4;
  float acc[4][4] = {};
  for (int it = 0; it < 4; ++it) {
    const int k0 = kbeg + it * 32;
#pragma unroll
    for (int i = 0; i < 2; ++i) {
      int idx = tid + i * 256;
      int r = idx >> 3, c = (idx & 7) << 2;
      const float4 a = *reinterpret_cast<const float4*>(h + (size_t)r * Eq + k0 + c);
      As[c + 0][r] = a.x; As[c + 1][r] = a.y; As[c + 2][r] = a.z; As[c + 3][r] = a.w;
      const float4 w = *reinterpret_cast<const float4*>(W + (size_t)(n0 + r) * Eq + k0 + c);
      Ws[c + 0][r] = w.x; Ws[c + 1][r] = w.y; Ws[c + 2][r] = w.z; Ws[c + 3][r] = w.w;
    }
    __syncthreads();
#pragma unroll
    for (int k = 0; k < 32; ++k) {
      float a[4], w[4];
#pragma unroll
      for (int i = 0; i < 4; ++i) { a[i] = As[k][ty * 4 + i]; w[i] = Ws[k][tx * 4 + i]; }
#pragma unroll
      for (int mi = 0; mi < 4; ++mi)
#pragma unroll
        for (int ni = 0; ni < 4; ++ni) acc[mi][ni] = fmaf(a[mi], w[ni], acc[mi][ni]);
    }
    __syncthreads();
  }
#pragma unroll
  for (int ni = 0; ni < 4; ++ni) {
    int n = n0 + tx * 4 + ni;
#pragma unroll
    for (int mi = 0; mi < 4; ++mi) P[(size_t)(ty * 4 + mi) * Npad + n] = acc[mi][ni];
  }
}

// K2: e + softmax -> alpha (+ alphas_out). grid = B, block 256.
__global__ __launch_bounds__(256) void attention_kernel(
    const float* __restrict__ Pah, const float* __restrict__ b_Uatt,
    const float* __restrict__ fproj, const float* __restrict__ v_att,
    const float* __restrict__ b_vatt, float* __restrict__ alpha,
    float* __restrict__ alphas_out, int t) {
  const int b = blockIdx.x;
  const int tid = threadIdx.x;
  const int lane = tid & 63, w = tid >> 6;
  __shared__ float ah[Eq];
  __shared__ float vs[Eq];
  __shared__ float ev[256];
  __shared__ float red[256];
  for (int i = tid; i < Eq; i += 256) {
    float s = b_Uatt[i];
#pragma unroll
    for (int sp = 0; sp < 4; ++sp) s += Pah[((size_t)sp * 64 + b) * Eq + i];
    ah[i] = s;
    vs[i] = v_att[i];
  }
  __syncthreads();
  const float bv = b_vatt[0];
  for (int p = w; p < Pq; p += 4) {
    const float* fp = fproj + ((size_t)b * Pq + p) * Eq;
    float s = 0.f;
#pragma unroll
    for (int j = 0; j < 8; ++j) {
      int k = j * 64 + lane;
      s = fmaf(tanhf(fp[k] + ah[k]), vs[k], s);
    }
#pragma unroll
    for (int off = 32; off > 0; off >>= 1) s += __shfl_xor(s, off);
    if (lane == 0) ev[p] = s + bv;
  }
  __syncthreads();
  float x = (tid < Pq) ? ev[tid] : -INFINITY;
  red[tid] = x;
  __syncthreads();
  for (int s = 128; s > 0; s >>= 1) {
    if (tid < s) red[tid] = fmaxf(red[tid], red[tid + s]);
    __syncthreads();
  }
  float mx = red[0];
  __syncthreads();
  float ex = (tid < Pq) ? expf(x - mx) : 0.f;
  red[tid] = ex;
  __syncthreads();
  for (int s = 128; s > 0; s >>= 1) {
    if (tid < s) red[tid] += red[tid + s];
    __syncthreads();
  }
  float inv = 1.f / red[0];
  if (tid < Pq) {
    float a = ex * inv;
    alpha[b * Pq + tid] = a;
    alphas_out[((size_t)b * Tq + t) * Pq + tid] = a;
  }
}

// K3: gated context from bf16 img. grid (B, 4), block 256; 2 d per thread.
__global__ __launch_bounds__(256) void ctx_kernel(const float* __restrict__ alpha,
                                                  const ushort* __restrict__ img16,
                                                  const float* __restrict__ Pfb,
                                                  const float* __restrict__ b_fbeta,
                                                  float* __restrict__ ctxg) {
  const int b = blockIdx.x;
  const int d0 = blockIdx.y * 512 + threadIdx.x;
  __shared__ float al[Pq];
  if (threadIdx.x < Pq) al[threadIdx.x] = alpha[b * Pq + threadIdx.x];
  float gp0 = b_fbeta[d0], gp1 = b_fbeta[d0 + 256];
#pragma unroll
  for (int sp = 0; sp < 4; ++sp) {
    const float* Pr = Pfb + ((size_t)sp * 64 + b) * Dq;
    gp0 += Pr[d0]; gp1 += Pr[d0 + 256];
  }
  __syncthreads();
  const ushort* ib = img16 + (size_t)b * Pq * Dq + d0;
  float s0 = 0.f, s1 = 0.f;
#pragma unroll 2
  for (int p = 0; p < Pq; ++p) {
    const ushort* r = ib + (size_t)p * Dq;
    float a = al[p];
    s0 = fmaf(a, bf2f(r[0]), s0);
    s1 = fmaf(a, bf2f(r[256]), s1);
  }
  ctxg[(size_t)b * Dq + d0] = s0 * sigf(gp0);
  ctxg[(size_t)b * Dq + d0 + 256] = s1 * sigf(gp1);
}

// K5: reduce gates partials + LSTM cell update.
__global__ __launch_bounds__(256) void lstm_epilogue(const float* __restrict__ P, int S,
                                                     const float* __restrict__ b_ih,
                                                     const float* __restrict__ b_hh,
                                                     const float* __restrict__ c,
                                                     float* __restrict__ h2,
                                                     float* __restrict__ c2) {
  int idx = blockIdx.x * 256 + threadIdx.x;
  int b = idx >> 9, e = idx & 511;
  float g0 = b_ih[e] + b_hh[e];
  float g1 = b_ih[Eq + e] + b_hh[Eq + e];
  float g2 = b_ih[2 * Eq + e] + b_hh[2 * Eq + e];
  float g3 = b_ih[3 * Eq + e] + b_hh[3 * Eq + e];
  for (int s = 0; s < S; ++s) {
    const float* Pr = P + ((size_t)s * 64 + b) * 2048;
    g0 += Pr[e]; g1 += Pr[Eq + e]; g2 += Pr[2 * Eq + e]; g3 += Pr[3 * Eq + e];
  }
  float ig = sigf(g0), fg = sigf(g1), gg = tanhf(g2), og = sigf(g3);
  float cn_ = fg * c[idx] + ig * gg;
  c2[idx] = cn_;
  h2[idx] = og * tanhf(cn_);
}

}  // namespace

extern "C" void kernel_launch(void* const* d_in, const int* in_sizes, int n_in,
                              void* d_out, int out_size, void* d_ws, size_t ws_size,
                              hipStream_t stream) {
  (void)in_sizes; (void)n_in; (void)out_size; (void)ws_size;
  const float* img      = (const float*)d_in[0];
  const int*   caps     = (const int*)d_in[1];
  const float* emb      = (const float*)d_in[2];
  const float* W_init_h = (const float*)d_in[3];
  const float* b_init_h = (const float*)d_in[4];
  const float* W_init_c = (const float*)d_in[5];
  const float* b_init_c = (const float*)d_in[6];
  const float* W_fbeta  = (const float*)d_in[7];
  const float* b_fbeta  = (const float*)d_in[8];
  const float* U_att    = (const float*)d_in[9];
  const float* b_Uatt   = (const float*)d_in[10];
  const float* W_att    = (const float*)d_in[11];
  const float* b_Watt   = (const float*)d_in[12];
  const float* v_att    = (const float*)d_in[13];
  const float* b_vatt   = (const float*)d_in[14];
  const float* W_ih     = (const float*)d_in[15];
  const float* b_ih     = (const float*)d_in[16];
  const float* W_hh     = (const float*)d_in[17];
  const float* b_hh     = (const float*)d_in[18];
  const float* W_out    = (const float*)d_in[19];
  const float* b_out    = (const float*)d_in[20];

  float* out = (float*)d_out;
  float* alphas_out = out + (size_t)Bq * Tq * Vq;

  constexpr size_t N_IMG = (size_t)Bq * Pq * Dq;  // 25,690,112
  float* ws = (float*)d_ws;
  ushort* img16  = (ushort*)ws; ws += N_IMG / 2;            // 51.4 MB
  ushort* Watt16 = (ushort*)ws; ws += (Eq * Dq) / 2;        // 2 MB
  float* fproj = ws; ws += N_IMG / Dq * Eq;                 // 25.7 MB (B*P*E)
  float* hseq  = ws; ws += (size_t)Tq * Bq * Eq;            // 4 MB
  float* h0    = ws; ws += Bq * Eq;
  float* c0    = ws; ws += Bq * Eq;
  float* c1    = ws; ws += Bq * Eq;
  float* alpha = ws; ws += Bq * Pq;
  float* ctxg  = ws; ws += Bq * Dq;
  float* buf   = ws; ws += (size_t)8 * Bq * Dq;             // 4 MB arena
  float* Pah = buf;                    // 4*64*512
  float* Pfb = buf + 4 * Bq * Eq;      // 4*64*2048
  float* Pg  = buf;                    // 8*64*2048
  float* initP = buf;                  // 8*64*512
  float* avg = buf + 8 * Bq * Eq;      // 64*2048

  // ---- Precompute ----
  cvt_bf16<<<(int)(N_IMG / 8 / 256), 256, 0, stream>>>(img, img16, (int)(N_IMG / 8));
  cvt_bf16<<<Eq * Dq / 8 / 256, 256, 0, stream>>>(W_att, Watt16, Eq * Dq / 8);
  avg_kernel<<<Bq * Dq / 256, 256, 0, stream>>>(img, avg);
  gemm_partial<0><<<dim3(Eq / 64, 8), 256, 0, stream>>>(avg, W_init_h, initP, Eq, Dq, 8, Eq,
                                                        nullptr, nullptr, nullptr, nullptr,
                                                        nullptr, 0);
  reduce_act_epilogue<ACT_TANH><<<Bq * Eq / 256, 256, 0, stream>>>(initP, b_init_h, h0, Eq, 8);
  gemm_partial<0><<<dim3(Eq / 64, 8), 256, 0, stream>>>(avg, W_init_c, initP, Eq, Dq, 8, Eq,
                                                        nullptr, nullptr, nullptr, nullptr,
                                                        nullptr, 0);
  reduce_act_epilogue<ACT_TANH><<<Bq * Eq / 256, 256, 0, stream>>>(initP, b_init_c, c0, Eq, 8);
  fproj_mfma<<<dim3(Bq * Pq / 128, Eq / 64), 256, 0, stream>>>(img16, Watt16, b_Watt, fproj);

  float* cc_ = c0; float* cn = c1;
  const float* hc = h0;
  for (int t = 0; t < Tq; ++t) {
    prestep_kernel<<<160, 256, 0, stream>>>(hc, U_att, W_fbeta, Pah, Pfb);
    attention_kernel<<<Bq, 256, 0, stream>>>(Pah, b_Uatt, fproj, v_att, b_vatt, alpha,
                                             alphas_out, t);
    ctx_kernel<<<dim3(Bq, 4), 256, 0, stream>>>(alpha, img16, Pfb, b_fbeta, ctxg);
    gemm_partial<1><<<dim3(Dq / 64, 8), 256, 0, stream>>>(nullptr, W_ih, Pg, Dq, 0, 12, Dq,
                                                          emb, caps, ctxg, hc, W_hh, t);
    float* hn = hseq + (size_t)t * Bq * Eq;
    lstm_epilogue<<<Bq * Eq / 256, 256, 0, stream>>>(Pg, 8, b_ih, b_hh, cc_, hn, cn);
    hc = hn;
    float* tmp = cc_; cc_ = cn; cn = tmp;
  }
  gemm_out_big<<<dim3(Tq * Bq / 128, 157), 256, 0, stream>>>(hseq, W_out, b_out, out);
}